// Round 11
// baseline (42.783 us; speedup 1.0000x reference)
//
#include <hip/hip_runtime.h>

// Structure exploited:
//   - every 5-node graph is complete with self-loops -> graph_conv == per-graph
//     mean followed by a dense layer; convs 2..4 are plain dense layers.
//   - no nonlinearity -> collapse weights: Wc = W1 W2 W3 W4 (64x64),
//     bc = ((b1 W2 + b2) W3 + b3) W4 + b4.
//   - out[g] = mean_{5 nodes}(concat(h,x)) @ Wc + bc ; 1/5 folded into WcQ.
//
// ws float layout:
//   A    = ws + 0      : [64][128]  = W1@W2
//   Bm   = ws + 8192   : [128][64]  = W3@W4
//   bT1  = ws + 16384  : [128]      = b1@W2 + b2
//   d1   = ws + 16512  : [64]       = b3@W4 + b4
//   WcQ  = ws + 16640  : [16][64][4] = 0.2*Wc in k-quad-major float4 layout:
//                         WcQ[(k>>2)*256 + o*4 + (k&3)] = Wc[k][o]*0.2
//   bc   = ws + 20736  : [64]       = bT1@Bm + d1

#define GB 16   // graphs per block in gcn_main (4 per wave) — R8-proven best

// ---------------- collapse1: A = W1@W2, Bm = W3@W4, bT1, d1 ----------------
// (R8-proven: 64 parallel blocks; R9 showed single-block serial is 8x worse.)
__global__ void __launch_bounds__(256) collapse1(
    const float* __restrict__ W1, const float* __restrict__ b1,
    const float* __restrict__ W2, const float* __restrict__ b2,
    const float* __restrict__ W3, const float* __restrict__ b3,
    const float* __restrict__ W4, const float* __restrict__ b4,
    float* __restrict__ ws) {
  __shared__ __align__(16) float smem[128 * 128 + 512];
  int tid = threadIdx.x;
  int bx = blockIdx.x;

  if (bx < 32) {
    float* W2s = smem;                 // 128x128
    float* w1s = smem + 16384;         // 2 rows of W1
    int i0 = bx * 2;
    {
      const float4* s = (const float4*)W2;
      float4* d = (float4*)W2s;
      #pragma unroll
      for (int j = 0; j < 16; ++j) d[tid + 256 * j] = s[tid + 256 * j];
      if (tid < 64) ((float4*)w1s)[tid] = ((const float4*)(W1 + i0 * 128))[tid];
    }
    __syncthreads();
    int il = tid >> 7, oo = tid & 127;
    float s0 = 0.f, s1 = 0.f, s2 = 0.f, s3 = 0.f;
    #pragma unroll 8
    for (int k = 0; k < 128; k += 4) {
      s0 += w1s[il * 128 + k + 0] * W2s[(k + 0) * 128 + oo];
      s1 += w1s[il * 128 + k + 1] * W2s[(k + 1) * 128 + oo];
      s2 += w1s[il * 128 + k + 2] * W2s[(k + 2) * 128 + oo];
      s3 += w1s[il * 128 + k + 3] * W2s[(k + 3) * 128 + oo];
    }
    ws[(i0 + il) * 128 + oo] = (s0 + s1) + (s2 + s3);
    if (bx == 0 && tid < 128) {        // bT1[o] = b2[o] + b1 @ W2
      float s = b2[tid];
      #pragma unroll 4
      for (int k = 0; k < 128; ++k) s += b1[k] * W2s[k * 128 + tid];
      ws[16384 + tid] = s;
    }
  } else {
    float* W4s = smem;                 // 128x64
    float* w3s = smem + 8192;          // 4 rows of W3
    int i0 = (bx - 32) * 4;
    {
      const float4* s = (const float4*)W4;
      float4* d = (float4*)W4s;
      #pragma unroll
      for (int j = 0; j < 8; ++j) d[tid + 256 * j] = s[tid + 256 * j];
      if (tid < 128) ((float4*)w3s)[tid] = ((const float4*)(W3 + i0 * 128))[tid];
    }
    __syncthreads();
    int il = tid >> 6, o = tid & 63;
    float s0 = 0.f, s1 = 0.f, s2 = 0.f, s3 = 0.f;
    #pragma unroll 8
    for (int k = 0; k < 128; k += 4) {
      s0 += w3s[il * 128 + k + 0] * W4s[(k + 0) * 64 + o];
      s1 += w3s[il * 128 + k + 1] * W4s[(k + 1) * 64 + o];
      s2 += w3s[il * 128 + k + 2] * W4s[(k + 2) * 64 + o];
      s3 += w3s[il * 128 + k + 3] * W4s[(k + 3) * 64 + o];
    }
    ws[8192 + (i0 + il) * 64 + o] = (s0 + s1) + (s2 + s3);
    if (bx == 32 && tid < 64) {        // d1[o] = b4[o] + b3 @ W4
      float s = b4[tid];
      #pragma unroll 4
      for (int k = 0; k < 128; ++k) s += b3[k] * W4s[k * 64 + tid];
      ws[16512 + tid] = s;
    }
  }
}

// ---------------- collapse2: WcQ = (A@Bm)*0.2 (k-quad layout), bc -----------
__global__ void __launch_bounds__(256) collapse2(float* __restrict__ ws) {
  __shared__ __align__(16) float smem[128 * 64 + 512];
  float* Bms = smem;                   // 128x64
  float* As  = smem + 8192;            // 4 rows of A
  int tid = threadIdx.x;
  int i0 = blockIdx.x * 4;
  {
    const float4* s = (const float4*)(ws + 8192);
    float4* d = (float4*)Bms;
    #pragma unroll
    for (int j = 0; j < 8; ++j) d[tid + 256 * j] = s[tid + 256 * j];
    if (tid < 128) ((float4*)As)[tid] = ((const float4*)(ws + i0 * 128))[tid];
  }
  __syncthreads();
  int il = tid >> 6, o = tid & 63;
  float s0 = 0.f, s1 = 0.f, s2 = 0.f, s3 = 0.f;
  #pragma unroll 8
  for (int k = 0; k < 128; k += 4) {
    s0 += As[il * 128 + k + 0] * Bms[(k + 0) * 64 + o];
    s1 += As[il * 128 + k + 1] * Bms[(k + 1) * 64 + o];
    s2 += As[il * 128 + k + 2] * Bms[(k + 2) * 64 + o];
    s3 += As[il * 128 + k + 3] * Bms[(k + 3) * 64 + o];
  }
  // WcQ[(i>>2)*256 + o*4 + (i&3)], i = i0+il (k index), i0 % 4 == 0
  ws[16640 + (i0 >> 2) * 256 + o * 4 + il] = ((s0 + s1) + (s2 + s3)) * 0.2f;
  if (blockIdx.x == 0 && tid < 64) {   // bc[o] = d1[o] + bT1 @ Bm
    float s = ws[16512 + tid];
    #pragma unroll 4
    for (int k = 0; k < 128; ++k) s += ws[16384 + k] * Bms[k * 64 + tid];
    ws[20736 + tid] = s;
  }
}

// ---------------- main fused kernel ----------------------------------------
// GB=16 graphs / 256-thread block (3125 blocks); ZERO LDS; barrier-free.
//   phase1: wave wv owns 4 graphs; lane = feature k; branchless base+stride
//           (h lanes 0..60 stride 61, x lanes 61..63 stride 3). sv[j] stays
//           in registers: lane k holds m[g_j][k].
//   phase2: per k-quad q: one coalesced float4 of WcQ from global (16 KB,
//           L2-resident) + 16 v_readlane (m[g][k] pulled from lane k's
//           register -> SGPR, VALU pipe) + 16 FMA w/ SGPR operand.
//           Replaces R8's 64 broadcast ds_read_b128/wave: the LDS pipe was
//           the largest modeled per-CU serial term (~12cyc x 64 x 49 waves).
__global__ void __launch_bounds__(256) gcn_main(
    const float* __restrict__ h, const float* __restrict__ x,
    const float* __restrict__ ws, float* __restrict__ out, int G) {
  int tid = threadIdx.x, wv = tid >> 6, lane = tid & 63;
  long gbase = (long)blockIdx.x * GB + (long)wv * 4;
  if (gbase >= G) return;

  float bco = ws[20736 + lane];
  bool ish = lane < 61;
  long st = ish ? 61 : 3;

  // ---- phase 1: 5-node feature sums, direct from global, branchless ----
  float sv0 = 0.f, sv1 = 0.f, sv2 = 0.f, sv3 = 0.f;
  {
    long g = gbase;
    const float* p0 = ish ? (h + (g+0) * 305 + lane) : (x + (g+0) * 15 + (lane - 61));
    const float* p1 = ish ? (h + (g+1) * 305 + lane) : (x + (g+1) * 15 + (lane - 61));
    const float* p2 = ish ? (h + (g+2) * 305 + lane) : (x + (g+2) * 15 + (lane - 61));
    const float* p3 = ish ? (h + (g+3) * 305 + lane) : (x + (g+3) * 15 + (lane - 61));
    if (g + 0 < G) sv0 = p0[0] + p0[st] + p0[2*st] + p0[3*st] + p0[4*st];
    if (g + 1 < G) sv1 = p1[0] + p1[st] + p1[2*st] + p1[3*st] + p1[4*st];
    if (g + 2 < G) sv2 = p2[0] + p2[st] + p2[2*st] + p2[3*st] + p2[4*st];
    if (g + 3 < G) sv3 = p3[0] + p3[st] + p3[2*st] + p3[3*st] + p3[4*st];
  }

  // ---- phase 2: out[g][o] = sum_k m[g][k] * Wc[k][o] + bc[o], o = lane ----
  // m[g][k] lives in lane k's sv_g register: pull via v_readlane (VALU, no LDS)
  {
    const float4* Wg = (const float4*)(ws + 16640);   // WcQ: Wg[q*64 + o]
    float a0 = bco, a1 = bco, a2 = bco, a3 = bco;

    #pragma unroll 4
    for (int q = 0; q < 16; ++q) {
      float4 w = Wg[q * 64 + lane];   // coalesced 1KB/wave, L2-resident
      #pragma unroll
      for (int e = 0; e < 4; ++e) {
        const int k = q * 4 + e;
        float we = (e == 0) ? w.x : (e == 1) ? w.y : (e == 2) ? w.z : w.w;
        float m0 = __int_as_float(__builtin_amdgcn_readlane(__float_as_int(sv0), k));
        float m1 = __int_as_float(__builtin_amdgcn_readlane(__float_as_int(sv1), k));
        float m2 = __int_as_float(__builtin_amdgcn_readlane(__float_as_int(sv2), k));
        float m3 = __int_as_float(__builtin_amdgcn_readlane(__float_as_int(sv3), k));
        a0 += m0 * we;
        a1 += m1 * we;
        a2 += m2 * we;
        a3 += m3 * we;
      }
    }

    long ob = gbase * 64 + lane;
    if (gbase + 0 < G) out[ob + 0]   = a0;
    if (gbase + 1 < G) out[ob + 64]  = a1;
    if (gbase + 2 < G) out[ob + 128] = a2;
    if (gbase + 3 < G) out[ob + 192] = a3;
  }
}

extern "C" void kernel_launch(void* const* d_in, const int* in_sizes, int n_in,
                              void* d_out, int out_size, void* d_ws, size_t ws_size,
                              hipStream_t stream) {
  const float* h  = (const float*)d_in[0];
  const float* x  = (const float*)d_in[1];
  // d_in[2] = src, d_in[3] = dst: structure known (complete 5-graphs), unused.
  const float* W1 = (const float*)d_in[4];
  const float* b1 = (const float*)d_in[5];
  const float* W2 = (const float*)d_in[6];
  const float* b2 = (const float*)d_in[7];
  const float* W3 = (const float*)d_in[8];
  const float* b3 = (const float*)d_in[9];
  const float* W4 = (const float*)d_in[10];
  const float* b4 = (const float*)d_in[11];
  float* ws = (float*)d_ws;
  float* out = (float*)d_out;

  int G = in_sizes[0] / 305;  // N*(IN-3) / (5*61)

  collapse1<<<64, 256, 0, stream>>>(W1, b1, W2, b2, W3, b3, W4, b4, ws);
  collapse2<<<16, 256, 0, stream>>>(ws);

  int blocks = (G + GB - 1) / GB;
  gcn_main<<<blocks, 256, 0, stream>>>(h, x, ws, out, G);
}

// Round 12
// 40.426 us; speedup vs baseline: 1.0583x; 1.0583x over previous
//
#include <hip/hip_runtime.h>
#include <hip/hip_cooperative_groups.h>

namespace cg = cooperative_groups;

// Structure exploited:
//   - every 5-node graph is complete with self-loops -> graph_conv == per-graph
//     mean + dense layer; convs 2..4 degenerate to dense layers (no nonlin).
//   - collapse: Wc = W1@W2@W3@W4, bc = ((b1W2+b2)W3+b3)W4+b4; 1/5 into WcQ.
//
// ws float layout:
//   A    = ws + 0      : [64][128]   = W1@W2
//   Bm   = ws + 8192   : [128][64]   = W3@W4
//   bT1  = ws + 16384  : [128]
//   d1   = ws + 16512  : [64]
//   WcQ  = ws + 16640  : [16][64][4] : WcQ[(k>>2)*256+o*4+(k&3)] = Wc[k][o]*0.2
//   bc   = ws + 20736  : [64]

#define AOFF   0
#define BOFF   8192
#define BT1OFF 16384
#define D1OFF  16512
#define WCQOFF 16640
#define BCOFF  20736

#define GB 16
#define NB 1024
#define NSLOT 4   // NB*NSLOT = 4096 >= NT = 3125

// ================= cooperative fused kernel ================================
// One launch. Blocks 0..128 fold the collapse stage-A under everyone's
// phase-1 (the HBM-heavy part); grid.sync; 65 blocks do stage-B; grid.sync;
// all blocks run the R8-proven phase-2 over their tiles.
__global__ void __launch_bounds__(256, 4) fused_all(
    const float* __restrict__ h, const float* __restrict__ x,
    const float* __restrict__ W1, const float* __restrict__ b1,
    const float* __restrict__ W2, const float* __restrict__ b2,
    const float* __restrict__ W3, const float* __restrict__ b3,
    const float* __restrict__ W4, const float* __restrict__ b4,
    float* __restrict__ ws, float* __restrict__ out, int G) {
  __shared__ __align__(16) float m_s[NSLOT][4][4][64];  // 16 KB
  __shared__ __align__(16) float redf[256];             //  1 KB

  cg::grid_group grid = cg::this_grid();
  const int tid = threadIdx.x, bid = blockIdx.x;
  const int wv = tid >> 6, lane = tid & 63;
  const int NT = (G + GB - 1) / GB;

  // ---- collapse stage A (129 low blocks) — overlaps phase 1 elsewhere ----
  if (bid < 64) {
    // A[bid][o] = sum_k W1[bid][k]*W2[k][o]; 2-way k-split + LDS reduce
    int kh = tid >> 7, o = tid & 127;
    const float* w1 = W1 + bid * 128 + kh * 64;          // wave-uniform
    const float* w2 = W2 + (kh * 64) * 128 + o;          // coalesced 512B
    float a0 = 0.f, a1 = 0.f, a2 = 0.f, a3 = 0.f;
    #pragma unroll 8
    for (int kk = 0; kk < 64; kk += 4) {
      a0 += w1[kk + 0] * w2[(kk + 0) * 128];
      a1 += w1[kk + 1] * w2[(kk + 1) * 128];
      a2 += w1[kk + 2] * w2[(kk + 2) * 128];
      a3 += w1[kk + 3] * w2[(kk + 3) * 128];
    }
    float a = (a0 + a1) + (a2 + a3);
    if (kh) redf[o] = a;
    __syncthreads();
    if (!kh) ws[AOFF + bid * 128 + o] = a + redf[o];
  } else if (bid < 128) {
    // Bm rows 2(bid-64), +1: Bm[r][o] = sum_k W3[r][k]*W4[k][o]
    int row_l = tid >> 7, kh = (tid >> 6) & 1, o = tid & 63;
    int row = (bid - 64) * 2 + row_l;
    const float* w3 = W3 + row * 128 + kh * 64;          // wave-uniform
    const float* w4 = W4 + (kh * 64) * 64 + o;           // coalesced 256B
    float a0 = 0.f, a1 = 0.f, a2 = 0.f, a3 = 0.f;
    #pragma unroll 8
    for (int kk = 0; kk < 64; kk += 4) {
      a0 += w3[kk + 0] * w4[(kk + 0) * 64];
      a1 += w3[kk + 1] * w4[(kk + 1) * 64];
      a2 += w3[kk + 2] * w4[(kk + 2) * 64];
      a3 += w3[kk + 3] * w4[(kk + 3) * 64];
    }
    float a = (a0 + a1) + (a2 + a3);
    if (kh) redf[row_l * 64 + o] = a;
    __syncthreads();
    if (!kh) ws[BOFF + row * 64 + o] = a + redf[row_l * 64 + o];
  } else if (bid == 128) {
    if (tid < 128) {                     // bT1 = b1@W2 + b2
      float s = b2[tid];
      #pragma unroll 4
      for (int k = 0; k < 128; ++k) s += b1[k] * W2[k * 128 + tid];
      ws[BT1OFF + tid] = s;
    } else if (tid < 192) {              // d1 = b3@W4 + b4
      int o = tid - 128;
      float s = b4[o];
      #pragma unroll 4
      for (int k = 0; k < 128; ++k) s += b3[k] * W4[k * 64 + o];
      ws[D1OFF + o] = s;
    }
  }

  // ---- phase 1: 5-node sums for up to NSLOT tiles -> LDS (R8 pattern) ----
  const bool ish = lane < 61;
  const long st = ish ? 61 : 3;
  #pragma unroll
  for (int s = 0; s < NSLOT; ++s) {
    int ts = bid + s * NB;
    if (ts < NT) {
      long gb = (long)ts * GB + (long)wv * 4;
      #pragma unroll
      for (int j = 0; j < 4; ++j) {
        long g = gb + j;
        float sv = 0.f;
        if (g < G) {
          const float* p = ish ? (h + g * 305 + lane) : (x + g * 15 + (lane - 61));
          sv = p[0] + p[st] + p[2 * st] + p[3 * st] + p[4 * st];
        }
        m_s[s][wv][j][lane] = sv;
      }
    }
  }

  grid.sync();

  // ---- collapse stage B (65 low blocks) ----
  if (bid < 64) {
    // Wc[bid][o] = sum_k A[bid][k]*Bm[k][o]; 4-way k-split + LDS reduce
    int kq = tid >> 6, o = tid & 63;
    const float* arow = ws + AOFF + bid * 128 + kq * 32;   // wave-uniform
    const float* bm = ws + BOFF + (kq * 32) * 64 + o;      // coalesced 256B
    float a0 = 0.f, a1 = 0.f, a2 = 0.f, a3 = 0.f;
    #pragma unroll 8
    for (int kk = 0; kk < 32; kk += 4) {
      a0 += arow[kk + 0] * bm[(kk + 0) * 64];
      a1 += arow[kk + 1] * bm[(kk + 1) * 64];
      a2 += arow[kk + 2] * bm[(kk + 2) * 64];
      a3 += arow[kk + 3] * bm[(kk + 3) * 64];
    }
    float a = (a0 + a1) + (a2 + a3);
    if (kq) redf[kq * 64 + o] = a;
    __syncthreads();
    if (!kq) {
      float t = a + redf[64 + o] + redf[128 + o] + redf[192 + o];
      ws[WCQOFF + (bid >> 2) * 256 + o * 4 + (bid & 3)] = t * 0.2f;
    }
  } else if (bid == 64 && tid < 64) {    // bc = bT1@Bm + d1
    float s = ws[D1OFF + tid];
    #pragma unroll 4
    for (int k = 0; k < 128; ++k) s += ws[BT1OFF + k] * ws[BOFF + k * 64 + tid];
    ws[BCOFF + tid] = s;
  }

  grid.sync();

  // ---- phase 2 (R8-proven): out[g][o] = m[g][:].Wc[:][o] + bc[o] ----
  float bco = ws[BCOFF + lane];
  const float4* Wg = (const float4*)(ws + WCQOFF);
  #pragma unroll 1
  for (int s = 0; s < NSLOT; ++s) {
    int ts = bid + s * NB;
    if (ts >= NT) break;
    long gb = (long)ts * GB + (long)wv * 4;
    const float4* m0 = (const float4*)&m_s[s][wv][0][0];
    const float4* m1 = (const float4*)&m_s[s][wv][1][0];
    const float4* m2 = (const float4*)&m_s[s][wv][2][0];
    const float4* m3 = (const float4*)&m_s[s][wv][3][0];
    float a0 = bco, a1 = bco, a2 = bco, a3 = bco;
    #pragma unroll 4
    for (int q = 0; q < 16; ++q) {
      float4 w = Wg[q * 64 + lane];    // coalesced, L2-resident
      float4 v0 = m0[q], v1 = m1[q], v2 = m2[q], v3 = m3[q];
      a0 += v0.x * w.x + v0.y * w.y + v0.z * w.z + v0.w * w.w;
      a1 += v1.x * w.x + v1.y * w.y + v1.z * w.z + v1.w * w.w;
      a2 += v2.x * w.x + v2.y * w.y + v2.z * w.z + v2.w * w.w;
      a3 += v3.x * w.x + v3.y * w.y + v3.z * w.z + v3.w * w.w;
    }
    long ob = gb * 64 + lane;
    if (gb + 0 < G) out[ob + 0]   = a0;
    if (gb + 1 < G) out[ob + 64]  = a1;
    if (gb + 2 < G) out[ob + 128] = a2;
    if (gb + 3 < G) out[ob + 192] = a3;
  }
}

// ================= fallback path (R8-proven 3-launch chain) ================
__global__ void __launch_bounds__(256) collapse1(
    const float* __restrict__ W1, const float* __restrict__ b1,
    const float* __restrict__ W2, const float* __restrict__ b2,
    const float* __restrict__ W3, const float* __restrict__ b3,
    const float* __restrict__ W4, const float* __restrict__ b4,
    float* __restrict__ ws) {
  __shared__ __align__(16) float smem[128 * 128 + 512];
  int tid = threadIdx.x;
  int bx = blockIdx.x;
  if (bx < 32) {
    float* W2s = smem;
    float* w1s = smem + 16384;
    int i0 = bx * 2;
    {
      const float4* s = (const float4*)W2;
      float4* d = (float4*)W2s;
      #pragma unroll
      for (int j = 0; j < 16; ++j) d[tid + 256 * j] = s[tid + 256 * j];
      if (tid < 64) ((float4*)w1s)[tid] = ((const float4*)(W1 + i0 * 128))[tid];
    }
    __syncthreads();
    int il = tid >> 7, oo = tid & 127;
    float s0 = 0.f, s1 = 0.f, s2 = 0.f, s3 = 0.f;
    #pragma unroll 8
    for (int k = 0; k < 128; k += 4) {
      s0 += w1s[il * 128 + k + 0] * W2s[(k + 0) * 128 + oo];
      s1 += w1s[il * 128 + k + 1] * W2s[(k + 1) * 128 + oo];
      s2 += w1s[il * 128 + k + 2] * W2s[(k + 2) * 128 + oo];
      s3 += w1s[il * 128 + k + 3] * W2s[(k + 3) * 128 + oo];
    }
    ws[(i0 + il) * 128 + oo] = (s0 + s1) + (s2 + s3);
    if (bx == 0 && tid < 128) {
      float s = b2[tid];
      #pragma unroll 4
      for (int k = 0; k < 128; ++k) s += b1[k] * W2s[k * 128 + tid];
      ws[BT1OFF + tid] = s;
    }
  } else {
    float* W4s = smem;
    float* w3s = smem + 8192;
    int i0 = (bx - 32) * 4;
    {
      const float4* s = (const float4*)W4;
      float4* d = (float4*)W4s;
      #pragma unroll
      for (int j = 0; j < 8; ++j) d[tid + 256 * j] = s[tid + 256 * j];
      if (tid < 128) ((float4*)w3s)[tid] = ((const float4*)(W3 + i0 * 128))[tid];
    }
    __syncthreads();
    int il = tid >> 6, o = tid & 63;
    float s0 = 0.f, s1 = 0.f, s2 = 0.f, s3 = 0.f;
    #pragma unroll 8
    for (int k = 0; k < 128; k += 4) {
      s0 += w3s[il * 128 + k + 0] * W4s[(k + 0) * 64 + o];
      s1 += w3s[il * 128 + k + 1] * W4s[(k + 1) * 64 + o];
      s2 += w3s[il * 128 + k + 2] * W4s[(k + 2) * 64 + o];
      s3 += w3s[il * 128 + k + 3] * W4s[(k + 3) * 64 + o];
    }
    ws[BOFF + (i0 + il) * 64 + o] = (s0 + s1) + (s2 + s3);
    if (bx == 32 && tid < 64) {
      float s = b4[tid];
      #pragma unroll 4
      for (int k = 0; k < 128; ++k) s += b3[k] * W4s[k * 64 + tid];
      ws[D1OFF + tid] = s;
    }
  }
}

__global__ void __launch_bounds__(256) collapse2(float* __restrict__ ws) {
  __shared__ __align__(16) float smem[128 * 64 + 512];
  float* Bms = smem;
  float* As  = smem + 8192;
  int tid = threadIdx.x;
  int i0 = blockIdx.x * 4;
  {
    const float4* s = (const float4*)(ws + BOFF);
    float4* d = (float4*)Bms;
    #pragma unroll
    for (int j = 0; j < 8; ++j) d[tid + 256 * j] = s[tid + 256 * j];
    if (tid < 128) ((float4*)As)[tid] = ((const float4*)(ws + i0 * 128))[tid];
  }
  __syncthreads();
  int il = tid >> 6, o = tid & 63;
  float s0 = 0.f, s1 = 0.f, s2 = 0.f, s3 = 0.f;
  #pragma unroll 8
  for (int k = 0; k < 128; k += 4) {
    s0 += As[il * 128 + k + 0] * Bms[(k + 0) * 64 + o];
    s1 += As[il * 128 + k + 1] * Bms[(k + 1) * 64 + o];
    s2 += As[il * 128 + k + 2] * Bms[(k + 2) * 64 + o];
    s3 += As[il * 128 + k + 3] * Bms[(k + 3) * 64 + o];
  }
  ws[WCQOFF + (i0 >> 2) * 256 + o * 4 + il] = ((s0 + s1) + (s2 + s3)) * 0.2f;
  if (blockIdx.x == 0 && tid < 64) {
    float s = ws[D1OFF + tid];
    #pragma unroll 4
    for (int k = 0; k < 128; ++k) s += ws[BT1OFF + k] * ws[BOFF + k * 64 + tid];
    ws[BCOFF + tid] = s;
  }
}

__global__ void __launch_bounds__(256) gcn_main(
    const float* __restrict__ h, const float* __restrict__ x,
    const float* __restrict__ ws, float* __restrict__ out, int G) {
  __shared__ __align__(16) float m_s[4][4][64];
  int tid = threadIdx.x, wv = tid >> 6, lane = tid & 63;
  long gbase = (long)blockIdx.x * GB + (long)wv * 4;
  if (gbase >= G) return;
  float bco = ws[BCOFF + lane];
  bool ish = lane < 61;
  long st = ish ? 61 : 3;
  float sv[4];
  #pragma unroll
  for (int j = 0; j < 4; ++j) {
    long g = gbase + j;
    if (g < G) {
      const float* p = ish ? (h + g * 305 + lane) : (x + g * 15 + (lane - 61));
      sv[j] = p[0] + p[st] + p[2 * st] + p[3 * st] + p[4 * st];
    } else sv[j] = 0.f;
  }
  #pragma unroll
  for (int j = 0; j < 4; ++j) m_s[wv][j][lane] = sv[j];
  {
    const float4* Wg = (const float4*)(ws + WCQOFF);
    const float4* m0 = (const float4*)&m_s[wv][0][0];
    const float4* m1 = (const float4*)&m_s[wv][1][0];
    const float4* m2 = (const float4*)&m_s[wv][2][0];
    const float4* m3 = (const float4*)&m_s[wv][3][0];
    float a0 = bco, a1 = bco, a2 = bco, a3 = bco;
    #pragma unroll 4
    for (int q = 0; q < 16; ++q) {
      float4 w = Wg[q * 64 + lane];
      float4 v0 = m0[q], v1 = m1[q], v2 = m2[q], v3 = m3[q];
      a0 += v0.x * w.x + v0.y * w.y + v0.z * w.z + v0.w * w.w;
      a1 += v1.x * w.x + v1.y * w.y + v1.z * w.z + v1.w * w.w;
      a2 += v2.x * w.x + v2.y * w.y + v2.z * w.z + v2.w * w.w;
      a3 += v3.x * w.x + v3.y * w.y + v3.z * w.z + v3.w * w.w;
    }
    long ob = gbase * 64 + lane;
    if (gbase + 0 < G) out[ob + 0]   = a0;
    if (gbase + 1 < G) out[ob + 64]  = a1;
    if (gbase + 2 < G) out[ob + 128] = a2;
    if (gbase + 3 < G) out[ob + 192] = a3;
  }
}

extern "C" void kernel_launch(void* const* d_in, const int* in_sizes, int n_in,
                              void* d_out, int out_size, void* d_ws, size_t ws_size,
                              hipStream_t stream) {
  const float* h  = (const float*)d_in[0];
  const float* x  = (const float*)d_in[1];
  // d_in[2] = src, d_in[3] = dst: structure known (complete 5-graphs), unused.
  const float* W1 = (const float*)d_in[4];
  const float* b1 = (const float*)d_in[5];
  const float* W2 = (const float*)d_in[6];
  const float* b2 = (const float*)d_in[7];
  const float* W3 = (const float*)d_in[8];
  const float* b3 = (const float*)d_in[9];
  const float* W4 = (const float*)d_in[10];
  const float* b4 = (const float*)d_in[11];
  float* ws = (float*)d_ws;
  float* out = (float*)d_out;
  int G = in_sizes[0] / 305;  // N*(IN-3) / (5*61)

  // runtime co-residency check: need >= 4 blocks/CU for NB=1024 on 256 CUs
  int maxB = 0;
  hipError_t qe = hipOccupancyMaxActiveBlocksPerMultiprocessor(&maxB, fused_all, 256, 0);
  bool coop = (qe == hipSuccess && maxB >= 4);

  if (coop) {
    void* params[] = {(void*)&h, (void*)&x,
                      (void*)&W1, (void*)&b1, (void*)&W2, (void*)&b2,
                      (void*)&W3, (void*)&b3, (void*)&W4, (void*)&b4,
                      (void*)&ws, (void*)&out, (void*)&G};
    hipError_t le = hipLaunchCooperativeKernel(fused_all, dim3(NB), dim3(256),
                                               params, 0, stream);
    if (le != hipSuccess) coop = false;
  }
  if (!coop) {
    collapse1<<<64, 256, 0, stream>>>(W1, b1, W2, b2, W3, b3, W4, b4, ws);
    collapse2<<<16, 256, 0, stream>>>(ws);
    gcn_main<<<(G + GB - 1) / GB, 256, 0, stream>>>(h, x, ws, out, G);
  }
}

// Round 13
// 38.058 us; speedup vs baseline: 1.1242x; 1.0622x over previous
//
#include <hip/hip_runtime.h>

// Structure exploited:
//   - every 5-node graph is complete with self-loops -> graph_conv == per-graph
//     mean + dense layer; convs 2..4 degenerate to dense layers (no nonlin).
//   - collapse: Wc = W1@W2@W3@W4, bc = ((b1W2+b2)W3+b3)W4+b4; 1/5 into WcQ.
//   - out[g] = mean5(concat(h,x)) @ Wc + bc.
//
// ws float layout:
//   WcQ = ws + 16640 : [16][64][4] : WcQ[(k>>2)*256 + o*4 + (k&3)] = Wc[k][o]*0.2
//   bc  = ws + 20736 : [64]

#define WCQOFF 16640
#define BCOFF  20736
#define GB 16   // graphs per block in gcn_main (4 per wave)

// ---------------- collapseX: ONE launch, 65 parallel blocks ----------------
// Blocks 0..63: block r computes row r of Wc = W1@W2@W3@W4 via the chain
//   arow = W1[r]@W2 (128) -> trow = arow@W3 (128) -> wc = trow@W4 (64),
// each stage 4-wave k-split (32 k each) + LDS reduce. Weights streamed
// directly from global (L2/L3-resident, coalesced b32) — no 64KB LDS staging,
// no dependent second kernel. Block 64: bias chain.
// R9 lesson: massive parallelism beats minimal launches; R13 lesson target:
// the OLD two-kernel prelude was ~20us of the 38.5us total.
__global__ void __launch_bounds__(256) collapseX(
    const float* __restrict__ W1, const float* __restrict__ b1,
    const float* __restrict__ W2, const float* __restrict__ b2,
    const float* __restrict__ W3, const float* __restrict__ b3,
    const float* __restrict__ W4, const float* __restrict__ b4,
    float* __restrict__ ws) {
  __shared__ float red[512];
  __shared__ float arow[128];
  __shared__ float trow[128];

  const int tid = threadIdx.x, wv = tid >> 6, lane = tid & 63;
  const int r = blockIdx.x;

  if (r < 64) {
    // ---- stage 1: arow[o] = sum_k W1[r][k] * W2[k][o] ----
    {
      const int kb = wv * 32;
      const float* w1p = W1 + r * 128 + kb;        // wave-uniform
      const float* w2p = W2 + kb * 128;
      float p0 = 0.f, p1 = 0.f;
      #pragma unroll 8
      for (int kk = 0; kk < 32; ++kk) {
        float w1 = w1p[kk];
        p0 += w1 * w2p[kk * 128 + lane];           // coalesced 256B
        p1 += w1 * w2p[kk * 128 + lane + 64];
      }
      red[wv * 128 + lane] = p0;
      red[wv * 128 + lane + 64] = p1;
    }
    __syncthreads();
    if (tid < 128) arow[tid] = red[tid] + red[128 + tid] + red[256 + tid] + red[384 + tid];
    __syncthreads();

    // ---- stage 2: trow[o] = sum_k arow[k] * W3[k][o] ----
    {
      const int kb = wv * 32;
      const float* w3p = W3 + kb * 128;
      float p0 = 0.f, p1 = 0.f;
      #pragma unroll 8
      for (int kk = 0; kk < 32; ++kk) {
        float a = arow[kb + kk];                   // LDS broadcast
        p0 += a * w3p[kk * 128 + lane];
        p1 += a * w3p[kk * 128 + lane + 64];
      }
      red[wv * 128 + lane] = p0;
      red[wv * 128 + lane + 64] = p1;
    }
    __syncthreads();
    if (tid < 128) trow[tid] = red[tid] + red[128 + tid] + red[256 + tid] + red[384 + tid];
    __syncthreads();

    // ---- stage 3: wc[o] = sum_k trow[k] * W4[k][o], o in [0,64) ----
    {
      const int kb = wv * 32;
      const float* w4p = W4 + kb * 64;
      float p = 0.f;
      #pragma unroll 8
      for (int kk = 0; kk < 32; ++kk) p += trow[kb + kk] * w4p[kk * 64 + lane];
      red[wv * 128 + lane] = p;                    // stride 128: conflict-free
    }
    __syncthreads();
    if (tid < 64) {
      float wc = red[tid] + red[128 + tid] + red[256 + tid] + red[384 + tid];
      // WcQ[(k>>2)*256 + o*4 + (k&3)] with k = r (gemv reduction index)
      ws[WCQOFF + (r >> 2) * 256 + tid * 4 + (r & 3)] = wc * 0.2f;
    }
  } else {
    // ---- block 64: bias chain bc = ((b1@W2+b2)@W3+b3)@W4+b4 ----
    if (tid < 128) {
      float s = b2[tid];
      #pragma unroll 4
      for (int k = 0; k < 128; ++k) s += b1[k] * W2[k * 128 + tid];
      arow[tid] = s;
    }
    __syncthreads();
    if (tid < 128) {
      float s = b3[tid];
      #pragma unroll 4
      for (int k = 0; k < 128; ++k) s += arow[k] * W3[k * 128 + tid];
      trow[tid] = s;
    }
    __syncthreads();
    if (tid < 64) {
      float s = b4[tid];
      #pragma unroll 4
      for (int k = 0; k < 128; ++k) s += trow[k] * W4[k * 64 + tid];
      ws[BCOFF + tid] = s;
    }
  }
}

// ---------------- main fused kernel (R9/R10-proven form, GB=16) ------------
// 3125 blocks x 256 threads; barrier-free; 4 KB LDS.
//   phase1: wave wv owns 4 graphs; lane = feature; branchless base+stride.
//   phase2: per k-quad: one coalesced float4 of WcQ (L2-resident) + 4
//           broadcast ds_read_b128 of m rows + 16 FMA; coalesced stores.
__global__ void __launch_bounds__(256) gcn_main(
    const float* __restrict__ h, const float* __restrict__ x,
    const float* __restrict__ ws, float* __restrict__ out, int G) {
  __shared__ __align__(16) float m_s[4][4][64];   // [wave][graph][feat], 4 KB

  int tid = threadIdx.x, wv = tid >> 6, lane = tid & 63;
  long gbase = (long)blockIdx.x * GB + (long)wv * 4;
  if (gbase >= G) return;

  float bco = ws[BCOFF + lane];
  bool ish = lane < 61;
  long st = ish ? 61 : 3;

  // ---- phase 1: 5-node feature sums, direct from global, branchless ----
  float sv[4];
  #pragma unroll
  for (int j = 0; j < 4; ++j) {
    long g = gbase + j;
    if (g < G) {
      const float* p = ish ? (h + g * 305 + lane) : (x + g * 15 + (lane - 61));
      sv[j] = p[0] + p[st] + p[2 * st] + p[3 * st] + p[4 * st];
    } else sv[j] = 0.f;
  }
  #pragma unroll
  for (int j = 0; j < 4; ++j) m_s[wv][j][lane] = sv[j];
  // wave-local LDS: no __syncthreads needed (lgkmcnt orders write->read)

  // ---- phase 2: out[g][o] = m[g][:] . Wc[:][o] + bc[o], o = lane ----
  {
    const float4* Wg = (const float4*)(ws + WCQOFF);
    const float4* m0 = (const float4*)&m_s[wv][0][0];
    const float4* m1 = (const float4*)&m_s[wv][1][0];
    const float4* m2 = (const float4*)&m_s[wv][2][0];
    const float4* m3 = (const float4*)&m_s[wv][3][0];
    float a0 = bco, a1 = bco, a2 = bco, a3 = bco;
    #pragma unroll 4
    for (int q = 0; q < 16; ++q) {
      float4 w = Wg[q * 64 + lane];   // coalesced 1KB/wave, L2-resident
      float4 v0 = m0[q], v1 = m1[q], v2 = m2[q], v3 = m3[q];
      a0 += v0.x * w.x + v0.y * w.y + v0.z * w.z + v0.w * w.w;
      a1 += v1.x * w.x + v1.y * w.y + v1.z * w.z + v1.w * w.w;
      a2 += v2.x * w.x + v2.y * w.y + v2.z * w.z + v2.w * w.w;
      a3 += v3.x * w.x + v3.y * w.y + v3.z * w.z + v3.w * w.w;
    }
    long ob = gbase * 64 + lane;
    if (gbase + 0 < G) out[ob + 0]   = a0;
    if (gbase + 1 < G) out[ob + 64]  = a1;
    if (gbase + 2 < G) out[ob + 128] = a2;
    if (gbase + 3 < G) out[ob + 192] = a3;
  }
}

extern "C" void kernel_launch(void* const* d_in, const int* in_sizes, int n_in,
                              void* d_out, int out_size, void* d_ws, size_t ws_size,
                              hipStream_t stream) {
  const float* h  = (const float*)d_in[0];
  const float* x  = (const float*)d_in[1];
  // d_in[2] = src, d_in[3] = dst: structure known (complete 5-graphs), unused.
  const float* W1 = (const float*)d_in[4];
  const float* b1 = (const float*)d_in[5];
  const float* W2 = (const float*)d_in[6];
  const float* b2 = (const float*)d_in[7];
  const float* W3 = (const float*)d_in[8];
  const float* b3 = (const float*)d_in[9];
  const float* W4 = (const float*)d_in[10];
  const float* b4 = (const float*)d_in[11];
  float* ws = (float*)d_ws;
  float* out = (float*)d_out;

  int G = in_sizes[0] / 305;  // N*(IN-3) / (5*61)

  collapseX<<<65, 256, 0, stream>>>(W1, b1, W2, b2, W3, b3, W4, b4, ws);
  gcn_main<<<(G + GB - 1) / GB, 256, 0, stream>>>(h, x, ws, out, G);
}